// Round 1
// baseline (651.446 us; speedup 1.0000x reference)
//
#include <hip/hip_runtime.h>
#include <math.h>

// Problem constants (from reference)
#define Bb 8
#define Ss 4096
#define Hh 1024
#define Rr 128
#define Nn 256
#define Mm (Bb*Ss)          // 32768 rows
#define LCH 128             // scan chunk length
#define NCHK (Ss/LCH)       // 32 chunks

static_assert(Ss % LCH == 0, "chunking");

__device__ __forceinline__ float sigmoidf_(float x) { return 1.0f / (1.0f + expf(-x)); }
__device__ __forceinline__ float softplusf_(float x) { return log1pf(expf(x)); }

// -------------------------------------------------------------------------
// C[M,N] = A[M,K] * B[N,K]^T  (both row-major, K contiguous)
// 128x128 block tile, BK=16, 256 threads, 8x8 register tile per thread.
// LDS stored K-major (As[kk][m]) so fragment reads are float4 (ds_read_b128).
// -------------------------------------------------------------------------
__global__ __launch_bounds__(256)
void gemm_nt128(const float* __restrict__ A, const float* __restrict__ Bm,
                float* __restrict__ C, int M, int N, int K)
{
    constexpr int BK = 16;
    __shared__ float As[BK][128 + 4];   // row stride 132 floats = 528 B (16B multiple)
    __shared__ float Bs[BK][128 + 4];
    const int tx = threadIdx.x & 15;
    const int ty = threadIdx.x >> 4;
    const int m0 = blockIdx.x * 128;
    const int n0 = blockIdx.y * 128;
    const int lr = threadIdx.x >> 2;        // 0..63 (tile row for loading)
    const int lc = (threadIdx.x & 3) * 4;   // 0,4,8,12 (k offset for loading)

    float acc[8][8] = {};

    for (int k0 = 0; k0 < K; k0 += BK) {
#pragma unroll
        for (int h = 0; h < 2; ++h) {
            const int r = lr + h * 64;
            const float4 av = *(const float4*)(A + (size_t)(m0 + r) * K + k0 + lc);
            As[lc + 0][r] = av.x; As[lc + 1][r] = av.y;
            As[lc + 2][r] = av.z; As[lc + 3][r] = av.w;
            const float4 bv = *(const float4*)(Bm + (size_t)(n0 + r) * K + k0 + lc);
            Bs[lc + 0][r] = bv.x; Bs[lc + 1][r] = bv.y;
            Bs[lc + 2][r] = bv.z; Bs[lc + 3][r] = bv.w;
        }
        __syncthreads();
#pragma unroll
        for (int kk = 0; kk < BK; ++kk) {
            float a[8], b[8];
            *(float4*)&a[0] = *(const float4*)&As[kk][ty * 8];
            *(float4*)&a[4] = *(const float4*)&As[kk][ty * 8 + 4];
            *(float4*)&b[0] = *(const float4*)&Bs[kk][tx * 8];
            *(float4*)&b[4] = *(const float4*)&Bs[kk][tx * 8 + 4];
#pragma unroll
            for (int i = 0; i < 8; ++i)
#pragma unroll
                for (int j = 0; j < 8; ++j)
                    acc[i][j] = fmaf(a[i], b[j], acc[i][j]);
        }
        __syncthreads();
    }

#pragma unroll
    for (int i = 0; i < 8; ++i) {
        float* crow = C + (size_t)(m0 + ty * 8 + i) * N + n0 + tx * 8;
        *(float4*)(crow)     = make_float4(acc[i][0], acc[i][1], acc[i][2], acc[i][3]);
        *(float4*)(crow + 4) = make_float4(acc[i][4], acc[i][5], acc[i][6], acc[i][7]);
    }
}

// -------------------------------------------------------------------------
// From z[M,R] compute b = z*k_sel^T, c = z*q_sel^T, v = z*v_sel^T (all [M,N]),
// then u = softplus(delta_log) * b * v. Stores u and c.
// 64x64 tile, BK=16, 4x4 register tiles (x3 accumulators).
// -------------------------------------------------------------------------
__global__ __launch_bounds__(256)
void proj_uc(const float* __restrict__ z, const float* __restrict__ ksel,
             const float* __restrict__ qsel, const float* __restrict__ vsel,
             const float* __restrict__ delta_log,
             float* __restrict__ u, float* __restrict__ c)
{
    constexpr int BK = 16;
    __shared__ float zs[BK][64 + 4];   // row stride 68 floats = 272 B (16B multiple)
    __shared__ float ks[BK][64 + 4];
    __shared__ float qs[BK][64 + 4];
    __shared__ float vs[BK][64 + 4];
    const int tx = threadIdx.x & 15;
    const int ty = threadIdx.x >> 4;
    const int m0 = blockIdx.x * 64;
    const int n0 = blockIdx.y * 64;
    const int lr = threadIdx.x >> 2;        // 0..63
    const int lc = (threadIdx.x & 3) * 4;   // 0,4,8,12

    float aB[4][4] = {}, aC[4][4] = {}, aV[4][4] = {};

    for (int k0 = 0; k0 < Rr; k0 += BK) {
        {
            const float4 zv = *(const float4*)(z + (size_t)(m0 + lr) * Rr + k0 + lc);
            zs[lc + 0][lr] = zv.x; zs[lc + 1][lr] = zv.y;
            zs[lc + 2][lr] = zv.z; zs[lc + 3][lr] = zv.w;
            const float4 kv = *(const float4*)(ksel + (size_t)(n0 + lr) * Rr + k0 + lc);
            ks[lc + 0][lr] = kv.x; ks[lc + 1][lr] = kv.y;
            ks[lc + 2][lr] = kv.z; ks[lc + 3][lr] = kv.w;
            const float4 qv = *(const float4*)(qsel + (size_t)(n0 + lr) * Rr + k0 + lc);
            qs[lc + 0][lr] = qv.x; qs[lc + 1][lr] = qv.y;
            qs[lc + 2][lr] = qv.z; qs[lc + 3][lr] = qv.w;
            const float4 vv = *(const float4*)(vsel + (size_t)(n0 + lr) * Rr + k0 + lc);
            vs[lc + 0][lr] = vv.x; vs[lc + 1][lr] = vv.y;
            vs[lc + 2][lr] = vv.z; vs[lc + 3][lr] = vv.w;
        }
        __syncthreads();
#pragma unroll
        for (int kk = 0; kk < BK; ++kk) {
            float za[4], kb[4], qb[4], vb[4];
            *(float4*)za = *(const float4*)&zs[kk][ty * 4];
            *(float4*)kb = *(const float4*)&ks[kk][tx * 4];
            *(float4*)qb = *(const float4*)&qs[kk][tx * 4];
            *(float4*)vb = *(const float4*)&vs[kk][tx * 4];
#pragma unroll
            for (int i = 0; i < 4; ++i)
#pragma unroll
                for (int j = 0; j < 4; ++j) {
                    aB[i][j] = fmaf(za[i], kb[j], aB[i][j]);
                    aC[i][j] = fmaf(za[i], qb[j], aC[i][j]);
                    aV[i][j] = fmaf(za[i], vb[j], aV[i][j]);
                }
        }
        __syncthreads();
    }

    float dl[4];
#pragma unroll
    for (int j = 0; j < 4; ++j) dl[j] = softplusf_(delta_log[n0 + tx * 4 + j]);

#pragma unroll
    for (int i = 0; i < 4; ++i) {
        const size_t row = (size_t)(m0 + ty * 4 + i);
        float4 uv, cv;
        uv.x = dl[0] * aB[i][0] * aV[i][0];
        uv.y = dl[1] * aB[i][1] * aV[i][1];
        uv.z = dl[2] * aB[i][2] * aV[i][2];
        uv.w = dl[3] * aB[i][3] * aV[i][3];
        cv.x = aC[i][0]; cv.y = aC[i][1]; cv.z = aC[i][2]; cv.w = aC[i][3];
        *(float4*)(u + row * Nn + n0 + tx * 4) = uv;
        *(float4*)(c + row * Nn + n0 + tx * 4) = cv;
    }
}

// -------------------------------------------------------------------------
// Scan pass A: per (b, chunk, n), chunk-local state contribution with s_init=0:
//   P = sum_{t in chunk} a^(L-1-t) * u_t   (computed as the recurrence itself)
// -------------------------------------------------------------------------
__global__ __launch_bounds__(256)
void scan_chunk_a(const float* __restrict__ u, const float* __restrict__ a_logit,
                  float* __restrict__ P)
{
    const int g = blockIdx.x * blockDim.x + threadIdx.x;   // B*NCHK*N threads
    const int n = g & (Nn - 1);
    const int rest = g >> 8;           // /Nn
    const int ch = rest & (NCHK - 1);
    const int b = rest >> 5;           // /NCHK
    const float a = sigmoidf_(a_logit[n]);
    const float* p = u + ((size_t)(b * Ss + ch * LCH)) * Nn + n;
    float s = 0.0f;
#pragma unroll 8
    for (int t = 0; t < LCH; ++t) {
        s = fmaf(a, s, *p);
        p += Nn;
    }
    P[((size_t)(b * NCHK + ch)) * Nn + n] = s;
}

// -------------------------------------------------------------------------
// Scan pass B (sequential over the 32 chunks; 2048 threads):
//   start[c] = state at entry of chunk c ; s' = a^L * s + P[c]
// Also writes final_state.
// -------------------------------------------------------------------------
__global__ __launch_bounds__(256)
void scan_mid(const float* __restrict__ P, const float* __restrict__ state0,
              const float* __restrict__ a_logit,
              float* __restrict__ start, float* __restrict__ final_state)
{
    const int g = blockIdx.x * blockDim.x + threadIdx.x;   // B*N threads
    const int n = g & (Nn - 1);
    const int b = g >> 8;
    const float a = sigmoidf_(a_logit[n]);
    float aL = a;
#pragma unroll
    for (int i = 0; i < 7; ++i) aL *= aL;                  // a^128 (LCH=128)
    float s = state0[g];
    for (int ch = 0; ch < NCHK; ++ch) {
        const size_t idx = ((size_t)(b * NCHK + ch)) * Nn + n;
        start[idx] = s;
        s = fmaf(aL, s, P[idx]);
    }
    final_state[g] = s;
}

// -------------------------------------------------------------------------
// Scan pass C: replay each chunk from its entry state, write ys = c * s
// IN PLACE over the u buffer (each element read once then overwritten).
// -------------------------------------------------------------------------
__global__ __launch_bounds__(256)
void scan_chunk_c(float* __restrict__ uy, const float* __restrict__ cm,
                  const float* __restrict__ start, const float* __restrict__ a_logit)
{
    const int g = blockIdx.x * blockDim.x + threadIdx.x;   // B*NCHK*N threads
    const int n = g & (Nn - 1);
    const int rest = g >> 8;
    const int ch = rest & (NCHK - 1);
    const int b = rest >> 5;
    const float a = sigmoidf_(a_logit[n]);
    float s = start[((size_t)(b * NCHK + ch)) * Nn + n];
    size_t idx = ((size_t)(b * Ss + ch * LCH)) * Nn + n;
#pragma unroll 8
    for (int t = 0; t < LCH; ++t) {
        s = fmaf(a, s, uy[idx]);
        uy[idx] = cm[idx] * s;
        idx += Nn;
    }
}

// -------------------------------------------------------------------------
extern "C" void kernel_launch(void* const* d_in, const int* in_sizes, int n_in,
                              void* d_out, int out_size, void* d_ws, size_t ws_size,
                              hipStream_t stream)
{
    const float* x         = (const float*)d_in[0];   // [B,S,H]
    const float* state0    = (const float*)d_in[1];   // [B,N]
    const float* in_basis  = (const float*)d_in[2];   // [R,H]
    const float* q_select  = (const float*)d_in[3];   // [N,R]
    const float* k_select  = (const float*)d_in[4];   // [N,R]
    const float* v_input   = (const float*)d_in[5];   // [N,R]
    const float* out_proj  = (const float*)d_in[6];   // [H,N]
    const float* a_logit   = (const float*)d_in[7];   // [N]
    const float* delta_log = (const float*)d_in[8];   // [N]

    float* out = (float*)d_out;                       // [B,S,H] then [B,N]
    float* final_state = out + (size_t)Mm * Hh;

    // workspace carve (fp32): z | u(->ys in place) | c | P | start  = ~84.4 MB
    char* ws = (char*)d_ws;
    float* z  = (float*)ws;
    float* u  = (float*)(ws + (size_t)Mm * Rr * 4);
    float* c  = (float*)(ws + (size_t)Mm * Rr * 4 + (size_t)Mm * Nn * 4);
    float* P  = (float*)(ws + (size_t)Mm * Rr * 4 + 2 * (size_t)Mm * Nn * 4);
    float* st = (float*)(ws + (size_t)Mm * Rr * 4 + 2 * (size_t)Mm * Nn * 4
                            + (size_t)Bb * NCHK * Nn * 4);

    // G1: z[M,R] = x[M,H] * in_basis[R,H]^T
    gemm_nt128<<<dim3(Mm / 128, Rr / 128), 256, 0, stream>>>(x, in_basis, z, Mm, Rr, Hh);

    // G2: u,c from z
    proj_uc<<<dim3(Mm / 64, Nn / 64), 256, 0, stream>>>(z, k_select, q_select, v_input,
                                                        delta_log, u, c);

    // chunked diagonal scan
    scan_chunk_a<<<(Bb * NCHK * Nn) / 256, 256, 0, stream>>>(u, a_logit, P);
    scan_mid<<<(Bb * Nn) / 256, 256, 0, stream>>>(P, state0, a_logit, st, final_state);
    scan_chunk_c<<<(Bb * NCHK * Nn) / 256, 256, 0, stream>>>(u, c, st, a_logit);

    // G4: out[M,H] = ys[M,N] * out_proj[H,N]^T   (ys lives in u)
    gemm_nt128<<<dim3(Mm / 128, Hh / 128), 256, 0, stream>>>(u, out_proj, out, Mm, Hh, Nn);
}

// Round 2
// 350.612 us; speedup vs baseline: 1.8580x; 1.8580x over previous
//
#include <hip/hip_runtime.h>
#include <math.h>

// Problem constants
#define Bb 8
#define Ss 4096
#define Hh 1024
#define Rr 128
#define Nn 256
#define Mm (Bb*Ss)          // 32768 rows
#define LCH 128             // scan chunk length
#define NCHK (Ss/LCH)       // 32 chunks

typedef __attribute__((ext_vector_type(8))) short bf16x8;   // 8 bf16 = 4 VGPRs
typedef __attribute__((ext_vector_type(4))) float f32x4;

__device__ __forceinline__ float sigmoidf_(float x) { return 1.0f / (1.0f + expf(-x)); }
__device__ __forceinline__ float softplusf_(float x) { return log1pf(expf(x)); }

// fp32 -> bf16 round-to-nearest-even
__device__ __forceinline__ unsigned short f2b(float f) {
    union { float f; unsigned int u; } v; v.f = f;
    return (unsigned short)((v.u + 0x7fffu + ((v.u >> 16) & 1u)) >> 16);
}
__device__ __forceinline__ float b2f(unsigned short h) {
    union { unsigned int u; float f; } v; v.u = ((unsigned int)h) << 16;
    return v.f;
}

// async global->LDS, 16B per lane; LDS dest = wave-uniform base + lane*16
__device__ __forceinline__ void gl_lds16(const void* g, void* l) {
    __builtin_amdgcn_global_load_lds(
        (const __attribute__((address_space(1))) void*)g,
        (__attribute__((address_space(3))) void*)l, 16, 0, 0);
}

// -------------------------------------------------------------------------
// cast kernels
// -------------------------------------------------------------------------
__global__ __launch_bounds__(256)
void cast_x(const float* __restrict__ src, unsigned short* __restrict__ dst)
{
    const size_t i = ((size_t)blockIdx.x * 256 + threadIdx.x) * 8;
    const float4 a = *(const float4*)(src + i);
    const float4 b = *(const float4*)(src + i + 4);
    uint4 o;
    o.x = (unsigned)f2b(a.x) | ((unsigned)f2b(a.y) << 16);
    o.y = (unsigned)f2b(a.z) | ((unsigned)f2b(a.w) << 16);
    o.z = (unsigned)f2b(b.x) | ((unsigned)f2b(b.y) << 16);
    o.w = (unsigned)f2b(b.z) | ((unsigned)f2b(b.w) << 16);
    *(uint4*)(dst + i) = o;
}

__global__ __launch_bounds__(256)
void cast_w(const float* __restrict__ s0, const float* __restrict__ s1,
            const float* __restrict__ s2, const float* __restrict__ s3,
            const float* __restrict__ s4,
            unsigned short* __restrict__ d0, unsigned short* __restrict__ d1,
            unsigned short* __restrict__ d2, unsigned short* __restrict__ d3,
            unsigned short* __restrict__ d4)
{
    const int i = blockIdx.x * 256 + threadIdx.x;
    // sizes: in_basis 131072 | k 32768 | q 32768 | v 32768 | out_proj 262144
    if (i < 131072)      d0[i] = f2b(s0[i]);
    else if (i < 163840) d1[i - 131072] = f2b(s1[i - 131072]);
    else if (i < 196608) d2[i - 163840] = f2b(s2[i - 163840]);
    else if (i < 229376) d3[i - 196608] = f2b(s3[i - 196608]);
    else                 d4[i - 229376] = f2b(s4[i - 229376]);
}

// -------------------------------------------------------------------------
// C[M,N] = A[M,K] * B[N,K]^T, bf16 inputs (K contiguous both), MFMA 16x16x32.
// 128x128 tile, BK=32, 256 threads = 4 waves, each wave 64x64 (4x4 MFMA tiles).
// -------------------------------------------------------------------------
template <bool OUT_BF16>
__global__ __launch_bounds__(256)
void mfma_nt(const unsigned short* __restrict__ A, const unsigned short* __restrict__ B,
             void* __restrict__ Cout, int M, int N, int K)
{
    __shared__ __align__(16) unsigned short As[128 * 32];   // row-major, 32 elems (64B) per row
    __shared__ __align__(16) unsigned short Bs[128 * 32];
    const int tid = threadIdx.x;
    const int wave = tid >> 6, lane = tid & 63;
    const int m0 = blockIdx.x * 128, n0 = blockIdx.y * 128;
    const int wm = (wave & 1) * 64, wn = (wave >> 1) * 64;
    const int quad = lane >> 4, lm = lane & 15;
    const int srow = lane >> 2;            // 0..15 within staging region
    const int skoff = (lane & 3) * 8;      // k element offset for staging
    const int r0 = wave * 2, r1 = r0 + 1;  // 16-row staging regions per wave

    f32x4 acc[4][4] = {};

    for (int k0 = 0; k0 < K; k0 += 32) {
        gl_lds16(A + (size_t)(m0 + r0 * 16 + srow) * K + k0 + skoff, &As[r0 * 512]);
        gl_lds16(A + (size_t)(m0 + r1 * 16 + srow) * K + k0 + skoff, &As[r1 * 512]);
        gl_lds16(B + (size_t)(n0 + r0 * 16 + srow) * K + k0 + skoff, &Bs[r0 * 512]);
        gl_lds16(B + (size_t)(n0 + r1 * 16 + srow) * K + k0 + skoff, &Bs[r1 * 512]);
        __syncthreads();
        bf16x8 af[4], bfv[4];
#pragma unroll
        for (int i = 0; i < 4; ++i)
            af[i] = *(const bf16x8*)&As[(wm + i * 16 + lm) * 32 + quad * 8];
#pragma unroll
        for (int j = 0; j < 4; ++j)
            bfv[j] = *(const bf16x8*)&Bs[(wn + j * 16 + lm) * 32 + quad * 8];
#pragma unroll
        for (int i = 0; i < 4; ++i)
#pragma unroll
            for (int j = 0; j < 4; ++j)
                acc[i][j] = __builtin_amdgcn_mfma_f32_16x16x32_bf16(af[i], bfv[j], acc[i][j], 0, 0, 0);
        __syncthreads();
    }

#pragma unroll
    for (int i = 0; i < 4; ++i) {
        const int rbase = m0 + wm + i * 16 + quad * 4;
#pragma unroll
        for (int j = 0; j < 4; ++j) {
            const int col = n0 + wn + j * 16 + lm;
#pragma unroll
            for (int r = 0; r < 4; ++r) {
                if (OUT_BF16)
                    ((unsigned short*)Cout)[(size_t)(rbase + r) * N + col] = f2b(acc[i][j][r]);
                else
                    ((float*)Cout)[(size_t)(rbase + r) * N + col] = acc[i][j][r];
            }
        }
    }
}

// -------------------------------------------------------------------------
// From z[M,128] bf16: b = z*Kw^T, c = z*Qw^T, v = z*Vw^T (N=256), then
// u = softplus(delta_log)*b*v. Writes u,c bf16. Same tile scheme, 3 acc sets.
// -------------------------------------------------------------------------
__global__ __launch_bounds__(256)
void proj_mfma(const unsigned short* __restrict__ Z, const unsigned short* __restrict__ Kw,
               const unsigned short* __restrict__ Qw, const unsigned short* __restrict__ Vw,
               const float* __restrict__ delta_log,
               unsigned short* __restrict__ U, unsigned short* __restrict__ C)
{
    __shared__ __align__(16) unsigned short zs[128 * 32];
    __shared__ __align__(16) unsigned short ks[128 * 32];
    __shared__ __align__(16) unsigned short qs[128 * 32];
    __shared__ __align__(16) unsigned short vs[128 * 32];
    const int tid = threadIdx.x;
    const int wave = tid >> 6, lane = tid & 63;
    const int m0 = blockIdx.x * 128, n0 = blockIdx.y * 128;
    const int wm = (wave & 1) * 64, wn = (wave >> 1) * 64;
    const int quad = lane >> 4, lm = lane & 15;
    const int srow = lane >> 2;
    const int skoff = (lane & 3) * 8;
    const int r0 = wave * 2, r1 = r0 + 1;

    f32x4 aB[4][4] = {}, aC[4][4] = {}, aV[4][4] = {};

    for (int k0 = 0; k0 < Rr; k0 += 32) {
        gl_lds16(Z  + (size_t)(m0 + r0 * 16 + srow) * Rr + k0 + skoff, &zs[r0 * 512]);
        gl_lds16(Z  + (size_t)(m0 + r1 * 16 + srow) * Rr + k0 + skoff, &zs[r1 * 512]);
        gl_lds16(Kw + (size_t)(n0 + r0 * 16 + srow) * Rr + k0 + skoff, &ks[r0 * 512]);
        gl_lds16(Kw + (size_t)(n0 + r1 * 16 + srow) * Rr + k0 + skoff, &ks[r1 * 512]);
        gl_lds16(Qw + (size_t)(n0 + r0 * 16 + srow) * Rr + k0 + skoff, &qs[r0 * 512]);
        gl_lds16(Qw + (size_t)(n0 + r1 * 16 + srow) * Rr + k0 + skoff, &qs[r1 * 512]);
        gl_lds16(Vw + (size_t)(n0 + r0 * 16 + srow) * Rr + k0 + skoff, &vs[r0 * 512]);
        gl_lds16(Vw + (size_t)(n0 + r1 * 16 + srow) * Rr + k0 + skoff, &vs[r1 * 512]);
        __syncthreads();
        bf16x8 zf[4], wf[4];
#pragma unroll
        for (int i = 0; i < 4; ++i)
            zf[i] = *(const bf16x8*)&zs[(wm + i * 16 + lm) * 32 + quad * 8];
#pragma unroll
        for (int j = 0; j < 4; ++j)
            wf[j] = *(const bf16x8*)&ks[(wn + j * 16 + lm) * 32 + quad * 8];
#pragma unroll
        for (int i = 0; i < 4; ++i)
#pragma unroll
            for (int j = 0; j < 4; ++j)
                aB[i][j] = __builtin_amdgcn_mfma_f32_16x16x32_bf16(zf[i], wf[j], aB[i][j], 0, 0, 0);
#pragma unroll
        for (int j = 0; j < 4; ++j)
            wf[j] = *(const bf16x8*)&qs[(wn + j * 16 + lm) * 32 + quad * 8];
#pragma unroll
        for (int i = 0; i < 4; ++i)
#pragma unroll
            for (int j = 0; j < 4; ++j)
                aC[i][j] = __builtin_amdgcn_mfma_f32_16x16x32_bf16(zf[i], wf[j], aC[i][j], 0, 0, 0);
#pragma unroll
        for (int j = 0; j < 4; ++j)
            wf[j] = *(const bf16x8*)&vs[(wn + j * 16 + lm) * 32 + quad * 8];
#pragma unroll
        for (int i = 0; i < 4; ++i)
#pragma unroll
            for (int j = 0; j < 4; ++j)
                aV[i][j] = __builtin_amdgcn_mfma_f32_16x16x32_bf16(zf[i], wf[j], aV[i][j], 0, 0, 0);
        __syncthreads();
    }

    float dl[4];
#pragma unroll
    for (int j = 0; j < 4; ++j)
        dl[j] = softplusf_(delta_log[n0 + wn + j * 16 + lm]);

#pragma unroll
    for (int i = 0; i < 4; ++i) {
        const int rbase = m0 + wm + i * 16 + quad * 4;
#pragma unroll
        for (int j = 0; j < 4; ++j) {
            const int col = n0 + wn + j * 16 + lm;
#pragma unroll
            for (int r = 0; r < 4; ++r) {
                const size_t idx = (size_t)(rbase + r) * Nn + col;
                U[idx] = f2b(dl[j] * aB[i][j][r] * aV[i][j][r]);
                C[idx] = f2b(aC[i][j][r]);
            }
        }
    }
}

// -------------------------------------------------------------------------
// Scan pass A: chunk-local contribution with s_init = 0 (u bf16)
// -------------------------------------------------------------------------
__global__ __launch_bounds__(256)
void scan_chunk_a(const unsigned short* __restrict__ u, const float* __restrict__ a_logit,
                  float* __restrict__ P)
{
    const int g = blockIdx.x * blockDim.x + threadIdx.x;
    const int n = g & (Nn - 1);
    const int rest = g >> 8;
    const int ch = rest & (NCHK - 1);
    const int b = rest >> 5;
    const float a = sigmoidf_(a_logit[n]);
    const unsigned short* p = u + ((size_t)(b * Ss + ch * LCH)) * Nn + n;
    float s = 0.0f;
#pragma unroll 8
    for (int t = 0; t < LCH; ++t) {
        s = fmaf(a, s, b2f(*p));
        p += Nn;
    }
    P[((size_t)(b * NCHK + ch)) * Nn + n] = s;
}

// -------------------------------------------------------------------------
// Scan pass B: sequential over 32 chunks; writes chunk entry states + final.
// -------------------------------------------------------------------------
__global__ __launch_bounds__(256)
void scan_mid(const float* __restrict__ P, const float* __restrict__ state0,
              const float* __restrict__ a_logit,
              float* __restrict__ start, float* __restrict__ final_state)
{
    const int g = blockIdx.x * blockDim.x + threadIdx.x;
    const int n = g & (Nn - 1);
    const int b = g >> 8;
    const float a = sigmoidf_(a_logit[n]);
    float aL = a;
#pragma unroll
    for (int i = 0; i < 7; ++i) aL *= aL;   // a^128
    float s = state0[g];
    for (int ch = 0; ch < NCHK; ++ch) {
        const size_t idx = ((size_t)(b * NCHK + ch)) * Nn + n;
        start[idx] = s;
        s = fmaf(aL, s, P[idx]);
    }
    final_state[g] = s;
}

// -------------------------------------------------------------------------
// Scan pass C: replay chunk from entry state; ys = c*s written in place (bf16)
// -------------------------------------------------------------------------
__global__ __launch_bounds__(256)
void scan_chunk_c(unsigned short* __restrict__ uy, const unsigned short* __restrict__ cm,
                  const float* __restrict__ start, const float* __restrict__ a_logit)
{
    const int g = blockIdx.x * blockDim.x + threadIdx.x;
    const int n = g & (Nn - 1);
    const int rest = g >> 8;
    const int ch = rest & (NCHK - 1);
    const int b = rest >> 5;
    const float a = sigmoidf_(a_logit[n]);
    float s = start[((size_t)(b * NCHK + ch)) * Nn + n];
    size_t idx = ((size_t)(b * Ss + ch * LCH)) * Nn + n;
#pragma unroll 8
    for (int t = 0; t < LCH; ++t) {
        s = fmaf(a, s, b2f(uy[idx]));
        uy[idx] = f2b(b2f(cm[idx]) * s);
        idx += Nn;
    }
}

// -------------------------------------------------------------------------
extern "C" void kernel_launch(void* const* d_in, const int* in_sizes, int n_in,
                              void* d_out, int out_size, void* d_ws, size_t ws_size,
                              hipStream_t stream)
{
    const float* x         = (const float*)d_in[0];
    const float* state0    = (const float*)d_in[1];
    const float* in_basis  = (const float*)d_in[2];
    const float* q_select  = (const float*)d_in[3];
    const float* k_select  = (const float*)d_in[4];
    const float* v_input   = (const float*)d_in[5];
    const float* out_proj  = (const float*)d_in[6];
    const float* a_logit   = (const float*)d_in[7];
    const float* delta_log = (const float*)d_in[8];

    float* out = (float*)d_out;
    float* final_state = out + (size_t)Mm * Hh;

    // workspace carve (~73.5 MB):
    // [xb 64MB (u/c alias inside after G1)] [zb 8MB] [weights ~1MB] [P][start]
    char* ws = (char*)d_ws;
    unsigned short* xb = (unsigned short*)ws;                        // 33554432 elems
    unsigned short* u  = (unsigned short*)ws;                        // alias (dead xb)
    unsigned short* c  = (unsigned short*)(ws + 16777216);           // alias (dead xb)
    unsigned short* zb = (unsigned short*)(ws + 67108864);           // 4194304 elems
    unsigned short* ib = (unsigned short*)(ws + 75497472);           // 131072
    unsigned short* kb = (unsigned short*)(ws + 75497472 + 262144);  // 32768
    unsigned short* qb = (unsigned short*)(ws + 75497472 + 327680);  // 32768
    unsigned short* vb = (unsigned short*)(ws + 75497472 + 393216);  // 32768
    unsigned short* ob = (unsigned short*)(ws + 75497472 + 458752);  // 262144
    float* P  = (float*)(ws + 76480512);                             // 65536 floats
    float* st = (float*)(ws + 76742656);                             // 65536 floats

    cast_x<<<Mm * Hh / (256 * 8), 256, 0, stream>>>(x, xb);
    cast_w<<<491520 / 256, 256, 0, stream>>>(in_basis, k_select, q_select, v_input, out_proj,
                                             ib, kb, qb, vb, ob);

    // G1: z[M,128] = x[M,1024] * in_basis[128,1024]^T  (bf16 out)
    mfma_nt<true><<<dim3(Mm / 128, Rr / 128), 256, 0, stream>>>(xb, ib, zb, Mm, Rr, Hh);

    // G2: u,c from z (bf16 out)
    proj_mfma<<<dim3(Mm / 128, Nn / 128), 256, 0, stream>>>(zb, kb, qb, vb, delta_log, u, c);

    // chunked diagonal scan
    scan_chunk_a<<<(Bb * NCHK * Nn) / 256, 256, 0, stream>>>(u, a_logit, P);
    scan_mid<<<(Bb * Nn) / 256, 256, 0, stream>>>(P, state0, a_logit, st, final_state);
    scan_chunk_c<<<(Bb * NCHK * Nn) / 256, 256, 0, stream>>>(u, c, st, a_logit);

    // G4: out[M,1024] = ys[M,256] * out_proj[1024,256]^T  (fp32 out)
    mfma_nt<false><<<dim3(Mm / 128, Hh / 128), 256, 0, stream>>>(u, ob, out, Mm, Hh, Nn);
}

// Round 3
// 325.584 us; speedup vs baseline: 2.0009x; 1.0769x over previous
//
#include <hip/hip_runtime.h>
#include <math.h>

// Problem constants
#define Bb 8
#define Ss 4096
#define Hh 1024
#define Rr 128
#define Nn 256
#define Mm (Bb*Ss)          // 32768 rows
#define LCH 128             // scan chunk length (== proj m-tile!)
#define NCHK (Ss/LCH)       // 32 chunks

typedef __attribute__((ext_vector_type(8))) short bf16x8;   // 8 bf16 = 4 VGPRs
typedef __attribute__((ext_vector_type(4))) float f32x4;

__device__ __forceinline__ float sigmoidf_(float x) { return 1.0f / (1.0f + expf(-x)); }
__device__ __forceinline__ float softplusf_(float x) { return log1pf(expf(x)); }

__device__ __forceinline__ unsigned short f2b(float f) {
    union { float f; unsigned int u; } v; v.f = f;
    return (unsigned short)((v.u + 0x7fffu + ((v.u >> 16) & 1u)) >> 16);
}
__device__ __forceinline__ float b2f(unsigned short h) {
    union { unsigned int u; float f; } v; v.u = ((unsigned int)h) << 16;
    return v.f;
}

__device__ __forceinline__ void gl_lds16(const void* g, void* l) {
    __builtin_amdgcn_global_load_lds(
        (const __attribute__((address_space(1))) void*)g,
        (__attribute__((address_space(3))) void*)l, 16, 0, 0);
}

// -------------------------------------------------------------------------
// cast weights to bf16 (tiny, one pass)
// -------------------------------------------------------------------------
__global__ __launch_bounds__(256)
void cast_w(const float* __restrict__ s0, const float* __restrict__ s1,
            const float* __restrict__ s2, const float* __restrict__ s3,
            const float* __restrict__ s4,
            unsigned short* __restrict__ d0, unsigned short* __restrict__ d1,
            unsigned short* __restrict__ d2, unsigned short* __restrict__ d3,
            unsigned short* __restrict__ d4)
{
    const int i = blockIdx.x * 256 + threadIdx.x;
    if (i < 131072)      d0[i] = f2b(s0[i]);
    else if (i < 163840) d1[i - 131072] = f2b(s1[i - 131072]);
    else if (i < 196608) d2[i - 163840] = f2b(s2[i - 163840]);
    else if (i < 229376) d3[i - 196608] = f2b(s3[i - 196608]);
    else                 d4[i - 229376] = f2b(s4[i - 229376]);
}

// -------------------------------------------------------------------------
// G1: z[M,128] = x[M,1024](fp32) * in_basis[128,1024](bf16)^T, z bf16.
// 64x128 tile, BK=32, 256 thr = 4 waves, wave tile 32x64 (2x4 MFMA tiles).
// x is loaded fp32 -> converted in-register -> ds_write (no cast pass).
// -------------------------------------------------------------------------
__global__ __launch_bounds__(256)
void g1_fused(const float* __restrict__ X, const unsigned short* __restrict__ IB,
              unsigned short* __restrict__ Z)
{
    __shared__ __align__(16) unsigned short As[64 * 32];    // 4 KB
    __shared__ __align__(16) unsigned short Bs[128 * 32];   // 8 KB
    const int tid = threadIdx.x;
    const int wave = tid >> 6, lane = tid & 63;
    const int m0 = blockIdx.x * 64;
    const int wm = (wave & 1) * 32, wn = (wave >> 1) * 64;
    const int quad = lane >> 4, lm = lane & 15;
    const int srow = lane >> 2;            // 0..15
    const int skoff = (lane & 3) * 8;      // bf16 elems
    const int arow = tid >> 3;             // 0..31
    const int akf = (tid & 7) * 4;         // fp32 elems 0..28

    f32x4 acc[2][4] = {};

    for (int k0 = 0; k0 < Hh; k0 += 32) {
        // A: fp32 -> bf16 staging (64 rows x 32 k)
#pragma unroll
        for (int q = 0; q < 2; ++q) {
            const int row = q * 32 + arow;
            const float4 v = *(const float4*)(X + (size_t)(m0 + row) * Hh + k0 + akf);
            uint2 o;
            o.x = (unsigned)f2b(v.x) | ((unsigned)f2b(v.y) << 16);
            o.y = (unsigned)f2b(v.z) | ((unsigned)f2b(v.w) << 16);
            *(uint2*)&As[row * 32 + akf] = o;
        }
        // B: async 16B staging (128 rows, regions 2w, 2w+1)
        gl_lds16(IB + (size_t)(2 * wave * 16 + srow) * Hh + k0 + skoff, &Bs[wave * 1024]);
        gl_lds16(IB + (size_t)((2 * wave + 1) * 16 + srow) * Hh + k0 + skoff, &Bs[wave * 1024 + 512]);
        __syncthreads();
        bf16x8 af[2], bfv[4];
#pragma unroll
        for (int i = 0; i < 2; ++i)
            af[i] = *(const bf16x8*)&As[(wm + i * 16 + lm) * 32 + quad * 8];
#pragma unroll
        for (int j = 0; j < 4; ++j)
            bfv[j] = *(const bf16x8*)&Bs[(wn + j * 16 + lm) * 32 + quad * 8];
#pragma unroll
        for (int i = 0; i < 2; ++i)
#pragma unroll
            for (int j = 0; j < 4; ++j)
                acc[i][j] = __builtin_amdgcn_mfma_f32_16x16x32_bf16(af[i], bfv[j], acc[i][j], 0, 0, 0);
        __syncthreads();
    }

#pragma unroll
    for (int i = 0; i < 2; ++i) {
        const int rbase = m0 + wm + i * 16 + quad * 4;
#pragma unroll
        for (int j = 0; j < 4; ++j) {
            const int col = wn + j * 16 + lm;
#pragma unroll
            for (int r = 0; r < 4; ++r)
                Z[(size_t)(rbase + r) * Rr + col] = f2b(acc[i][j][r]);
        }
    }
}

// -------------------------------------------------------------------------
// G2: from z[M,128] bf16: b=z*Kw^T, c=z*Qw^T, v=z*Vw^T; u=softplus(dl)*b*v.
// Block tile 128m x 64n, wave tile 64x32 (4x2 tiles x3 accs = 96 VGPR).
// Epilogue ALSO computes P[chunk,n] (chunk-local scan contribution) since a
// block's 128 rows are exactly one scan chunk. Deletes scan_chunk_a.
// -------------------------------------------------------------------------
__global__ __launch_bounds__(256)
void proj_mfma(const unsigned short* __restrict__ Zm, const unsigned short* __restrict__ Kw,
               const unsigned short* __restrict__ Qw, const unsigned short* __restrict__ Vw,
               const float* __restrict__ delta_log, const float* __restrict__ a_logit,
               unsigned short* __restrict__ U, unsigned short* __restrict__ C,
               float* __restrict__ Pout)
{
    __shared__ __align__(16) char smem[34816];
    unsigned short* zs = (unsigned short*)smem;            // 128x32 = 8 KB
    unsigned short* ks = (unsigned short*)(smem + 8192);   // 64x32 = 4 KB
    unsigned short* qs = (unsigned short*)(smem + 12288);
    unsigned short* vs = (unsigned short*)(smem + 16384);
    float* uL = (float*)smem;                              // 128 x 66 fp32 (union, post-loop)
    float* pcomb = (float*)(smem + 33792);                 // 4 x 64 fp32

    const int tid = threadIdx.x;
    const int wave = tid >> 6, lane = tid & 63;
    const int m0 = blockIdx.x * 128, n0 = blockIdx.y * 64;
    const int wm = (wave & 1) * 64, wn = (wave >> 1) * 32;
    const int quad = lane >> 4, lm = lane & 15;
    const int srow = lane >> 2;
    const int skoff = (lane & 3) * 8;

    f32x4 aB[4][2] = {}, aC[4][2] = {}, aV[4][2] = {};

    for (int k0 = 0; k0 < Rr; k0 += 32) {
        gl_lds16(Zm + (size_t)(m0 + 2 * wave * 16 + srow) * Rr + k0 + skoff, &zs[wave * 1024]);
        gl_lds16(Zm + (size_t)(m0 + (2 * wave + 1) * 16 + srow) * Rr + k0 + skoff, &zs[wave * 1024 + 512]);
        gl_lds16(Kw + (size_t)(n0 + wave * 16 + srow) * Rr + k0 + skoff, &ks[wave * 512]);
        gl_lds16(Qw + (size_t)(n0 + wave * 16 + srow) * Rr + k0 + skoff, &qs[wave * 512]);
        gl_lds16(Vw + (size_t)(n0 + wave * 16 + srow) * Rr + k0 + skoff, &vs[wave * 512]);
        __syncthreads();
        bf16x8 zf[4], wf[2];
#pragma unroll
        for (int i = 0; i < 4; ++i)
            zf[i] = *(const bf16x8*)&zs[(wm + i * 16 + lm) * 32 + quad * 8];
#pragma unroll
        for (int j = 0; j < 2; ++j)
            wf[j] = *(const bf16x8*)&ks[(wn + j * 16 + lm) * 32 + quad * 8];
#pragma unroll
        for (int i = 0; i < 4; ++i)
#pragma unroll
            for (int j = 0; j < 2; ++j)
                aB[i][j] = __builtin_amdgcn_mfma_f32_16x16x32_bf16(zf[i], wf[j], aB[i][j], 0, 0, 0);
#pragma unroll
        for (int j = 0; j < 2; ++j)
            wf[j] = *(const bf16x8*)&qs[(wn + j * 16 + lm) * 32 + quad * 8];
#pragma unroll
        for (int i = 0; i < 4; ++i)
#pragma unroll
            for (int j = 0; j < 2; ++j)
                aC[i][j] = __builtin_amdgcn_mfma_f32_16x16x32_bf16(zf[i], wf[j], aC[i][j], 0, 0, 0);
#pragma unroll
        for (int j = 0; j < 2; ++j)
            wf[j] = *(const bf16x8*)&vs[(wn + j * 16 + lm) * 32 + quad * 8];
#pragma unroll
        for (int i = 0; i < 4; ++i)
#pragma unroll
            for (int j = 0; j < 2; ++j)
                aV[i][j] = __builtin_amdgcn_mfma_f32_16x16x32_bf16(zf[i], wf[j], aV[i][j], 0, 0, 0);
        __syncthreads();
    }

    float dl[2];
#pragma unroll
    for (int j = 0; j < 2; ++j)
        dl[j] = softplusf_(delta_log[n0 + wn + j * 16 + lm]);

    // epilogue: write u,c (bf16, global) and u (fp32) to LDS tile for P
#pragma unroll
    for (int i = 0; i < 4; ++i) {
        const int lrow = wm + i * 16 + quad * 4;
        const int rbase = m0 + lrow;
#pragma unroll
        for (int j = 0; j < 2; ++j) {
            const int col = wn + j * 16 + lm;        // 0..63 within block
            const int gcol = n0 + col;
#pragma unroll
            for (int r = 0; r < 4; ++r) {
                const float uval = dl[j] * aB[i][j][r] * aV[i][j][r];
                const size_t idx = (size_t)(rbase + r) * Nn + gcol;
                U[idx] = f2b(uval);
                C[idx] = f2b(aC[i][j][r]);
                uL[(lrow + r) * 66 + col] = uval;
            }
        }
    }
    __syncthreads();

    // chunk-local scan contribution P (zero-init): 4 segments of 32 rows/col
    const int colp = tid & 63, seg = tid >> 6;
    const float a = sigmoidf_(a_logit[n0 + colp]);
    float l = 0.0f;
#pragma unroll 8
    for (int r = 0; r < 32; ++r)
        l = fmaf(a, l, uL[(seg * 32 + r) * 66 + colp]);
    pcomb[seg * 64 + colp] = l;
    __syncthreads();
    if (tid < 64) {
        float a32 = a;
#pragma unroll
        for (int i = 0; i < 5; ++i) a32 *= a32;      // a^32
        const float Pv = ((pcomb[tid] * a32 + pcomb[64 + tid]) * a32
                          + pcomb[128 + tid]) * a32 + pcomb[192 + tid];
        Pout[(size_t)blockIdx.x * Nn + n0 + tid] = Pv;
    }
}

// -------------------------------------------------------------------------
// Scan pass B: sequential over 32 chunks (fully unrolled); entry states + final.
// -------------------------------------------------------------------------
__global__ __launch_bounds__(256)
void scan_mid(const float* __restrict__ P, const float* __restrict__ state0,
              const float* __restrict__ a_logit,
              float* __restrict__ start, float* __restrict__ final_state)
{
    const int g = blockIdx.x * blockDim.x + threadIdx.x;
    const int n = g & (Nn - 1);
    const int b = g >> 8;
    const float a = sigmoidf_(a_logit[n]);
    float aL = a;
#pragma unroll
    for (int i = 0; i < 7; ++i) aL *= aL;   // a^128
    float s = state0[g];
#pragma unroll
    for (int ch = 0; ch < NCHK; ++ch) {
        const size_t idx = ((size_t)(b * NCHK + ch)) * Nn + n;
        start[idx] = s;
        s = fmaf(aL, s, P[idx]);
    }
    final_state[g] = s;
}

// -------------------------------------------------------------------------
// Scan pass C: replay chunk from entry state; ys = c*s in place (bf16)
// -------------------------------------------------------------------------
__global__ __launch_bounds__(256)
void scan_chunk_c(unsigned short* __restrict__ uy, const unsigned short* __restrict__ cm,
                  const float* __restrict__ start, const float* __restrict__ a_logit)
{
    const int g = blockIdx.x * blockDim.x + threadIdx.x;
    const int n = g & (Nn - 1);
    const int rest = g >> 8;
    const int ch = rest & (NCHK - 1);
    const int b = rest >> 5;
    const float a = sigmoidf_(a_logit[n]);
    float s = start[((size_t)(b * NCHK + ch)) * Nn + n];
    size_t idx = ((size_t)(b * Ss + ch * LCH)) * Nn + n;
#pragma unroll 8
    for (int t = 0; t < LCH; ++t) {
        s = fmaf(a, s, b2f(uy[idx]));
        uy[idx] = f2b(b2f(cm[idx]) * s);
        idx += Nn;
    }
}

// -------------------------------------------------------------------------
// G4: out[M,1024](fp32) = ys[M,256](bf16) * out_proj[1024,256](bf16)^T
// 128x128 tile, BK=32, 4 waves, wave 64x64 (4x4 tiles).
// -------------------------------------------------------------------------
__global__ __launch_bounds__(256)
void mfma_nt_f32(const unsigned short* __restrict__ A, const unsigned short* __restrict__ B,
                 float* __restrict__ Cout, int M, int N, int K)
{
    __shared__ __align__(16) unsigned short As[128 * 32];
    __shared__ __align__(16) unsigned short Bs[128 * 32];
    const int tid = threadIdx.x;
    const int wave = tid >> 6, lane = tid & 63;
    const int m0 = blockIdx.x * 128, n0 = blockIdx.y * 128;
    const int wm = (wave & 1) * 64, wn = (wave >> 1) * 64;
    const int quad = lane >> 4, lm = lane & 15;
    const int srow = lane >> 2;
    const int skoff = (lane & 3) * 8;
    const int r0 = wave * 2, r1 = r0 + 1;

    f32x4 acc[4][4] = {};

    for (int k0 = 0; k0 < K; k0 += 32) {
        gl_lds16(A + (size_t)(m0 + r0 * 16 + srow) * K + k0 + skoff, &As[r0 * 512]);
        gl_lds16(A + (size_t)(m0 + r1 * 16 + srow) * K + k0 + skoff, &As[r1 * 512]);
        gl_lds16(B + (size_t)(n0 + r0 * 16 + srow) * K + k0 + skoff, &Bs[r0 * 512]);
        gl_lds16(B + (size_t)(n0 + r1 * 16 + srow) * K + k0 + skoff, &Bs[r1 * 512]);
        __syncthreads();
        bf16x8 af[4], bfv[4];
#pragma unroll
        for (int i = 0; i < 4; ++i)
            af[i] = *(const bf16x8*)&As[(wm + i * 16 + lm) * 32 + quad * 8];
#pragma unroll
        for (int j = 0; j < 4; ++j)
            bfv[j] = *(const bf16x8*)&Bs[(wn + j * 16 + lm) * 32 + quad * 8];
#pragma unroll
        for (int i = 0; i < 4; ++i)
#pragma unroll
            for (int j = 0; j < 4; ++j)
                acc[i][j] = __builtin_amdgcn_mfma_f32_16x16x32_bf16(af[i], bfv[j], acc[i][j], 0, 0, 0);
        __syncthreads();
    }

#pragma unroll
    for (int i = 0; i < 4; ++i) {
        const int rbase = m0 + wm + i * 16 + quad * 4;
#pragma unroll
        for (int j = 0; j < 4; ++j) {
            const int col = n0 + wn + j * 16 + lm;
#pragma unroll
            for (int r = 0; r < 4; ++r)
                Cout[(size_t)(rbase + r) * N + col] = acc[i][j][r];
        }
    }
}

// -------------------------------------------------------------------------
extern "C" void kernel_launch(void* const* d_in, const int* in_sizes, int n_in,
                              void* d_out, int out_size, void* d_ws, size_t ws_size,
                              hipStream_t stream)
{
    const float* x         = (const float*)d_in[0];
    const float* state0    = (const float*)d_in[1];
    const float* in_basis  = (const float*)d_in[2];
    const float* q_select  = (const float*)d_in[3];
    const float* k_select  = (const float*)d_in[4];
    const float* v_input   = (const float*)d_in[5];
    const float* out_proj  = (const float*)d_in[6];
    const float* a_logit   = (const float*)d_in[7];
    const float* delta_log = (const float*)d_in[8];

    float* out = (float*)d_out;
    float* final_state = out + (size_t)Mm * Hh;

    // workspace carve (~43.5 MB)
    char* ws = (char*)d_ws;
    unsigned short* u  = (unsigned short*)ws;                    // 16 MB
    unsigned short* c  = (unsigned short*)(ws + 16777216);       // 16 MB
    unsigned short* zb = (unsigned short*)(ws + 33554432);       // 8 MB
    unsigned short* ib = (unsigned short*)(ws + 41943040);       // 256 KB
    unsigned short* kb = (unsigned short*)(ws + 42205184);       // 64 KB
    unsigned short* qb = (unsigned short*)(ws + 42270720);       // 64 KB
    unsigned short* vb = (unsigned short*)(ws + 42336256);       // 64 KB
    unsigned short* ob = (unsigned short*)(ws + 42401792);       // 512 KB
    float* P  = (float*)(ws + 42926080);                         // 256 KB
    float* st = (float*)(ws + 43188224);                         // 256 KB

    cast_w<<<491520 / 256, 256, 0, stream>>>(in_basis, k_select, q_select, v_input, out_proj,
                                             ib, kb, qb, vb, ob);

    // G1: z = x * in_basis^T (fp32 x read directly, bf16 out)
    g1_fused<<<Mm / 64, 256, 0, stream>>>(x, ib, zb);

    // G2: u,c (+ chunk contributions P) from z
    proj_mfma<<<dim3(Mm / 128, Nn / 64), 256, 0, stream>>>(zb, kb, qb, vb,
                                                           delta_log, a_logit, u, c, P);

    // chunk-boundary scan + replay
    scan_mid<<<(Bb * Nn) / 256, 256, 0, stream>>>(P, state0, a_logit, st, final_state);
    scan_chunk_c<<<(Bb * NCHK * Nn) / 256, 256, 0, stream>>>(u, c, st, a_logit);

    // G4: out = ys * out_proj^T (fp32 out)
    mfma_nt_f32<<<dim3(Mm / 128, Hh / 128), 256, 0, stream>>>(u, ob, out, Mm, Hh, Nn);
}